// Round 5
// baseline (179.687 us; speedup 1.0000x reference)
//
#include <hip/hip_runtime.h>

#define SPACE_TOK 63
#define INV_T 14.285714285714286f          /* 1/0.07 */
#define SA_SCALE 20.609929155556595f       /* log2(e)/0.07 ; also the static max bound */
#define LN2F 0.6931471805599453f

typedef __attribute__((ext_vector_type(8))) short bf16x8;
typedef __attribute__((ext_vector_type(4))) float f32x4;

// ---- workspace byte offsets ----
#define O_CECM   0                         /* 1024 f */
#define O_CEM    4096                      /* 1024 f */
#define O_CEC    8192                      /* 1024 f */
#define O_PEXP2  14464                     /* 8*4096 f -> ends 145536 */
#define O_DIAG2  145536                    /* 4096 f  -> 161920 */
#define O_PEXP3  161920                    /* 8*1024 f -> 194688 */
#define O_DIAG3  194688                    /* 1024 f  -> 198784 */
#define O_A2     198848                    /* swizzled bf16 */
#define SZ_A2    (4096*128*2)
#define O_P2     (O_A2 + SZ_A2)
#define O_A3     (O_P2 + SZ_A2)
#define SZ_A3    (1024*128*2)
#define O_P3     (O_A3 + SZ_A3)
/* segment-scan results */
#define O_SEGM   (O_P3 + SZ_A3)            /* 32 ints: segment counts */
#define O_SEGN   (O_SEGM + 128)            /* 32 ints: next-space-after-quarter */
#define O_SEGL   (O_SEGN + 128)            /* 32 x 512 ushort segment positions */
#define SEG_CAP  512
/* word partials: 8-way segment-split -> 4096 part-blocks */
#define O_WP2    (O_SEGL + 32*SEG_CAP*2)   /* 4096 f */
#define O_WC2    (O_WP2 + 16384)           /* 256 f */
#define NWORD_PARTS 8

#define SMEM_A 18048   /* norm_body: 16896 + 1024 + 128 ; scan fits inside */
#define SMEM_B 4608    /* max(nce 4608, word 32, ce 48) */

__device__ inline unsigned short f2bf(float x) {
  union { float f; unsigned int u; } c; c.f = x;
  unsigned int r = c.u + 0x7fffu + ((c.u >> 16) & 1u);
  return (unsigned short)(r >> 16);
}

// ================= dispatch A: norm2(256) | norm3(64) | scan(32) =================
// norm writes A/P in MFMA-fragment-contiguous (swizzled) layout:
//   slot(row,c) = (row>>4)*2048 + (c>>5)*512 + (((c>>3)&3)*16 + (row&15))*8 + (c&7)
__device__ void norm_body(char* smem, const float* __restrict__ emb, int L,
                          unsigned short* __restrict__ Abf, unsigned short* __restrict__ Pbf,
                          int b, int l0) {
  float (*tile)[33] = (float(*)[33])smem;                 // 128*33*4 = 16896 B
  float (*np8)[32]  = (float(*)[32])(smem + 16896);       // 1024 B
  float* scl        = (float*)(smem + 16896 + 1024);      // 128 B
  int tid = threadIdx.x;
  int lx = tid & 31, cq = tid >> 5;
  const float* eb = emb + (size_t)b * 128 * L + l0;
  for (int c = cq; c < 128; c += 8) tile[c][lx] = eb[(size_t)c * L + lx];
  __syncthreads();
  {
    float s = 0.f;
    for (int c = cq; c < 128; c += 8) { float x = tile[c][lx]; s += x * x; }
    np8[cq][lx] = s;
  }
  __syncthreads();
  if (tid < 32) {
    float t = 0.f;
#pragma unroll
    for (int g = 0; g < 8; ++g) t += np8[g][tid];
    float nrm = fmaxf(sqrtf(t), 1e-12f);
    scl[tid] = ((tid & 1) ? 1.0f : SA_SCALE) / nrm;  // even l -> anchor (scaled)
  }
  __syncthreads();
  int c = tid & 127, lh = tid >> 7;
  int half = L >> 1;
  int k = c >> 5, quad = (c >> 3) & 3, j = c & 7;
  for (int lp = lh; lp < 32; lp += 2) {
    int l = l0 + lp;
    int row = b * half + (l >> 1);
    unsigned short v = f2bf(tile[c][lp] * scl[lp]);
    unsigned short* dst = (l & 1) ? Pbf : Abf;
    dst[(size_t)(row >> 4) * 2048 + k * 512 + ((quad << 4) + (row & 15)) * 8 + j] = v;
  }
}

// one scan block per (b, tq): prefix-scan spaces in the quarter, find first space
// of the following quarters; publish to ws so word blocks skip this work.
__device__ void scan_body(char* smem, const int* __restrict__ targets,
                          char* __restrict__ ws, int s) {
  int* sc       = (int*)smem;             // 1024 B
  int* snext_sh = (int*)(smem + 1024);    // 4 B
  int tid = threadIdx.x;
  int b = s >> 2, tq = s & 3;
  const int* tb = targets + b * 4096;
  int tbase = tq * 1024;
  int4 tok = ((const int4*)(tb + tbase))[tid];
  int f0 = (tok.x == SPACE_TOK), f1 = (tok.y == SPACE_TOK),
      f2 = (tok.z == SPACE_TOK), f3 = (tok.w == SPACE_TOK);
  int cnt = f0 + f1 + f2 + f3;
  sc[tid] = cnt;
  __syncthreads();
  for (int off = 1; off < 256; off <<= 1) {
    int v = (tid >= off) ? sc[tid - off] : 0;
    __syncthreads();
    sc[tid] += v;
    __syncthreads();
  }
  int base = sc[tid] - cnt;
  int p = tbase + tid * 4;
  unsigned short* segl = (unsigned short*)(ws + O_SEGL) + s * SEG_CAP;
  if (f0) { if (base < SEG_CAP) segl[base] = (unsigned short)p;       base++; }
  if (f1) { if (base < SEG_CAP) segl[base] = (unsigned short)(p + 1); base++; }
  if (f2) { if (base < SEG_CAP) segl[base] = (unsigned short)(p + 2); base++; }
  if (f3) { if (base < SEG_CAP) segl[base] = (unsigned short)(p + 3); base++; }
  int m = sc[255];
  if (tid == 0) *snext_sh = -1;
  __syncthreads();
  if (m > 0) {
    for (int wstart = tbase + 1024; wstart < 4096 && *snext_sh < 0; wstart += 1024) {
      int t = wstart + tid * 4;
      int4 tk = ((const int4*)tb)[t >> 2];
      int found = 0x7fffffff;
      if (tk.x == SPACE_TOK) found = t;
      else if (tk.y == SPACE_TOK) found = t + 1;
      else if (tk.z == SPACE_TOK) found = t + 2;
      else if (tk.w == SPACE_TOK) found = t + 3;
#pragma unroll
      for (int mm = 1; mm < 64; mm <<= 1) found = min(found, __shfl_xor(found, mm));
      if ((tid & 63) == 0) sc[tid >> 6] = found;
      __syncthreads();
      if (tid == 0) {
        int f = min(min(sc[0], sc[1]), min(sc[2], sc[3]));
        if (f != 0x7fffffff) *snext_sh = f;
      }
      __syncthreads();
    }
  }
  if (tid == 0) {
    ((int*)(ws + O_SEGM))[s] = min(m, SEG_CAP);
    ((int*)(ws + O_SEGN))[s] = *snext_sh;
  }
}

__global__ void __launch_bounds__(256) fusedA_kernel(const float* __restrict__ c2,
                                                     const float* __restrict__ c3,
                                                     const int* __restrict__ targets,
                                                     char* __restrict__ ws) {
  extern __shared__ char smem[];
  int bid = blockIdx.x;
  if (bid < 256) {
    norm_body(smem, c2, 1024, (unsigned short*)(ws + O_A2), (unsigned short*)(ws + O_P2),
              bid & 7, (bid >> 3) * 32);
  } else if (bid < 320) {
    int nb = bid - 256;
    norm_body(smem, c3, 256, (unsigned short*)(ws + O_A3), (unsigned short*)(ws + O_P3),
              nb & 7, (nb >> 3) * 32);
  } else {
    scan_body(smem, targets, ws, bid - 320);
  }
}

// ================= dispatch B bodies =================
// word: 8-way segment-split — part p of block w handles segments i = p, p+8, ...
// Collapses the per-block serial segment chain (the fusedB drain tail).
__device__ void word_body(char* smem, const float* __restrict__ wp,
                          const float* __restrict__ cf,
                          char* __restrict__ ws, int bid) {
  float* wacc = (float*)smem;             // 16 B
  int tid = threadIdx.x;
  int p = bid & (NWORD_PARTS - 1);
  int w = bid >> 3;
  int z = w & 15, tq = (w >> 4) & 3, b = w >> 6;
  int s = b * 4 + tq;
  int m     = ((const int*)(ws + O_SEGM))[s];
  int snext = ((const int*)(ws + O_SEGN))[s];
  const unsigned short* segl = (const unsigned short*)(ws + O_SEGL) + s * SEG_CAP;
  int wave = tid >> 6, lane = tid & 63;
  int dbase = z * 32 + wave * 8;
  const float* r0 = cf + ((size_t)(b * 512 + dbase)) * 4096;
  float myacc = 0.f;
  float lcnt = 0.f;
  for (int i = p; i < m; i += NWORD_PARTS) {
    int t0 = segl[i];
    int t1 = (i + 1 < m) ? (int)segl[i + 1] : snext;
    if (t1 < 0) break;
    int seglen = t1 - t0 - 1;
    if (seglen <= 0) continue;
    lcnt += 1.0f;
    int wpos = t0 >> 1;
    float invc = 1.0f / (float)seglen;
    float pred = 0.f;   // prefetch the scattered word_preds read so it overlaps the c-loop
    if (lane < 8) pred = wp[((size_t)(b * 512 + dbase + lane)) * 2048 + wpos];
    int c0 = (t0 + 1) >> 2;
    int c1 = (t1 + 3) >> 2;
    float s0 = 0.f, s1 = 0.f, s2 = 0.f, s3 = 0.f, s4 = 0.f, s5 = 0.f, s6 = 0.f, s7 = 0.f;
    for (int c = c0 + lane; c < c1; c += 64) {
      int tbp = c << 2;
      float4 v0 = *(const float4*)(r0 + 0 * 4096 + tbp);
      float4 v1 = *(const float4*)(r0 + 1 * 4096 + tbp);
      float4 v2 = *(const float4*)(r0 + 2 * 4096 + tbp);
      float4 v3 = *(const float4*)(r0 + 3 * 4096 + tbp);
      float4 v4 = *(const float4*)(r0 + 4 * 4096 + tbp);
      float4 v5 = *(const float4*)(r0 + 5 * 4096 + tbp);
      float4 v6 = *(const float4*)(r0 + 6 * 4096 + tbp);
      float4 v7 = *(const float4*)(r0 + 7 * 4096 + tbp);
      float m0 = (tbp + 0 > t0 && tbp + 0 < t1) ? 1.f : 0.f;
      float m1 = (tbp + 1 > t0 && tbp + 1 < t1) ? 1.f : 0.f;
      float m2 = (tbp + 2 > t0 && tbp + 2 < t1) ? 1.f : 0.f;
      float m3 = (tbp + 3 > t0 && tbp + 3 < t1) ? 1.f : 0.f;
      s0 += v0.x * m0 + v0.y * m1 + v0.z * m2 + v0.w * m3;
      s1 += v1.x * m0 + v1.y * m1 + v1.z * m2 + v1.w * m3;
      s2 += v2.x * m0 + v2.y * m1 + v2.z * m2 + v2.w * m3;
      s3 += v3.x * m0 + v3.y * m1 + v3.z * m2 + v3.w * m3;
      s4 += v4.x * m0 + v4.y * m1 + v4.z * m2 + v4.w * m3;
      s5 += v5.x * m0 + v5.y * m1 + v5.z * m2 + v5.w * m3;
      s6 += v6.x * m0 + v6.y * m1 + v6.z * m2 + v6.w * m3;
      s7 += v7.x * m0 + v7.y * m1 + v7.z * m2 + v7.w * m3;
    }
#pragma unroll
    for (int mm = 1; mm < 64; mm <<= 1) {
      s0 += __shfl_xor(s0, mm); s1 += __shfl_xor(s1, mm);
      s2 += __shfl_xor(s2, mm); s3 += __shfl_xor(s3, mm);
      s4 += __shfl_xor(s4, mm); s5 += __shfl_xor(s5, mm);
      s6 += __shfl_xor(s6, mm); s7 += __shfl_xor(s7, mm);
    }
    if (lane < 8) {
      float sv = (lane == 0) ? s0 : (lane == 1) ? s1 : (lane == 2) ? s2 : (lane == 3) ? s3
               : (lane == 4) ? s4 : (lane == 5) ? s5 : (lane == 6) ? s6 : s7;
      float mean = sv * invc;
      float diff = pred - mean;
      myacc += diff * diff;
    }
  }
#pragma unroll
  for (int mm = 1; mm < 8; mm <<= 1) myacc += __shfl_xor(myacc, mm);
  if (lane == 0) wacc[wave] = myacc;
  __syncthreads();
  if (tid == 0) {
    ((float*)(ws + O_WP2))[bid] = (wacc[0] + wacc[1] + wacc[2] + wacc[3]) * (1.0f / 512.0f);
    if (z == 0) ((float*)(ws + O_WC2))[(w >> 4) * NWORD_PARTS + p] = lcnt;
  }
}

// nce: swizzled fragment loads — every global load is 64 lanes x 16 B contiguous.
__device__ void nce_body(char* smem, const unsigned short* __restrict__ A,
                         const unsigned short* __restrict__ P, int n, int sliceJ,
                         int blk_i, int s, float* __restrict__ pexp,
                         float* __restrict__ diag) {
  int tid = threadIdx.x;
  int wave = tid >> 6, lane = tid & 63;
  int col = lane & 15, quad = lane >> 4;
  int I0 = blk_i * 16;
  const unsigned short* At = A + (size_t)blk_i * 2048 + lane * 8;
  bf16x8 a0 = *(const bf16x8*)(At);
  bf16x8 a1 = *(const bf16x8*)(At + 512);
  bf16x8 a2 = *(const bf16x8*)(At + 1024);
  bf16x8 a3 = *(const bf16x8*)(At + 1536);
  float rl0 = 0.f, rl1 = 0.f, rl2 = 0.f, rl3 = 0.f;
  float dcap = 0.f;
  int perW = sliceJ >> 2;
  int J0w = s * sliceJ + wave * perW, Jend = J0w + perW;
#pragma unroll 2
  for (int J = J0w; J < Jend; J += 16) {
    const unsigned short* Pt = P + (size_t)(J >> 4) * 2048 + lane * 8;
    bf16x8 b0 = *(const bf16x8*)(Pt);
    bf16x8 b1 = *(const bf16x8*)(Pt + 512);
    bf16x8 b2 = *(const bf16x8*)(Pt + 1024);
    bf16x8 b3 = *(const bf16x8*)(Pt + 1536);
    f32x4 cfr = {0.f, 0.f, 0.f, 0.f};
    cfr = __builtin_amdgcn_mfma_f32_16x16x32_bf16(a0, b0, cfr, 0, 0, 0);
    cfr = __builtin_amdgcn_mfma_f32_16x16x32_bf16(a1, b1, cfr, 0, 0, 0);
    cfr = __builtin_amdgcn_mfma_f32_16x16x32_bf16(a2, b2, cfr, 0, 0, 0);
    cfr = __builtin_amdgcn_mfma_f32_16x16x32_bf16(a3, b3, cfr, 0, 0, 0);
    rl0 += exp2f(cfr[0] - SA_SCALE);
    rl1 += exp2f(cfr[1] - SA_SCALE);
    rl2 += exp2f(cfr[2] - SA_SCALE);
    rl3 += exp2f(cfr[3] - SA_SCALE);
    if (J == I0) {
      int r = col - (quad << 2);
      if (r == 0) dcap = cfr[0];
      else if (r == 1) dcap = cfr[1];
      else if (r == 2) dcap = cfr[2];
      else if (r == 3) dcap = cfr[3];
    }
  }
  float (*part)[16][17] = (float(*)[16][17])smem;          // padded: no 4-way conflict
  float (*dpart)[16]    = (float(*)[16])(smem + 4352);
  part[wave][(quad << 2) + 0][col] = rl0;
  part[wave][(quad << 2) + 1][col] = rl1;
  part[wave][(quad << 2) + 2][col] = rl2;
  part[wave][(quad << 2) + 3][col] = rl3;
  if (quad == (col >> 2)) dpart[wave][col] = dcap;
  __syncthreads();
  {
    int rrow = tid >> 4, cc = tid & 15;
    float sv = 0.f, d = 0.f;
#pragma unroll
    for (int ww = 0; ww < 4; ++ww) { sv += part[ww][rrow][cc]; d += dpart[ww][rrow]; }
#pragma unroll
    for (int mm = 1; mm < 16; mm <<= 1) sv += __shfl_xor(sv, mm);
    if (cc == 0) {
      pexp[I0 + rrow] = sv;
      if (I0 >= s * sliceJ && I0 < (s + 1) * sliceJ) diag[I0 + rrow] = d;
    }
  }
}

__device__ void ce_body(char* smem, const float* __restrict__ logits,
                        const int* __restrict__ targets, const float* __restrict__ mask,
                        char* ws, int cb) {
  int tid = threadIdx.x;
  int wave = tid >> 6, lane = tid & 63;
  int rbase = cb * 32 + wave * 8;
  float4 v[8];
  float mk[8];
  int tg[8];
#pragma unroll
  for (int rr = 0; rr < 8; ++rr) v[rr] = ((const float4*)logits)[(size_t)(rbase + rr) * 64 + lane];
#pragma unroll
  for (int rr = 0; rr < 8; ++rr) { tg[rr] = targets[rbase + rr]; mk[rr] = mask[rbase + rr]; }
  float aCM = 0.f, aM = 0.f, aC = 0.f;
#pragma unroll
  for (int rr = 0; rr < 8; ++rr) {
    float e = __expf(v[rr].x) + __expf(v[rr].y) + __expf(v[rr].z) + __expf(v[rr].w);
#pragma unroll
    for (int m = 1; m < 64; m <<= 1) e += __shfl_xor(e, m);
    int t = tg[rr];
    int q = t & 3;
    float sel = (q == 0) ? v[rr].x : (q == 1) ? v[rr].y : (q == 2) ? v[rr].z : v[rr].w;
    float xt = __shfl(sel, t >> 2);
    float ce = __logf(e) - xt;
    aCM += ce * mk[rr]; aM += mk[rr]; aC += ce;
  }
  float (*red)[3] = (float(*)[3])smem;
  if (lane == 0) { red[wave][0] = aCM; red[wave][1] = aM; red[wave][2] = aC; }
  __syncthreads();
  if (tid == 0) {
    ((float*)(ws + O_CECM))[cb] = red[0][0] + red[1][0] + red[2][0] + red[3][0];
    ((float*)(ws + O_CEM ))[cb] = red[0][1] + red[1][1] + red[2][1] + red[3][1];
    ((float*)(ws + O_CEC ))[cb] = red[0][2] + red[1][2] + red[2][2] + red[3][2];
  }
}

// ===== dispatch B: word-parts(4096) | ce(1024) | nce2(2048) | nce3(512) = 7680 ======
__global__ void __launch_bounds__(256) fusedB_kernel(const float* __restrict__ logits,
                                                     const float* __restrict__ wp,
                                                     const float* __restrict__ cf,
                                                     const int* __restrict__ targets,
                                                     const float* __restrict__ mask,
                                                     char* __restrict__ ws) {
  extern __shared__ char smem[];
  int bid = blockIdx.x;
  if (bid < 4096) {
    word_body(smem, wp, cf, ws, bid);
  } else if (bid < 5120) {
    ce_body(smem, logits, targets, mask, ws, bid - 4096);
  } else if (bid < 7168) {
    int nb = bid - 5120;
    nce_body(smem, (const unsigned short*)(ws + O_A2), (const unsigned short*)(ws + O_P2),
             4096, 512, nb >> 3, nb & 7,
             (float*)(ws + O_PEXP2) + (nb & 7) * 4096, (float*)(ws + O_DIAG2));
  } else {
    int nb = bid - 7168;
    nce_body(smem, (const unsigned short*)(ws + O_A3), (const unsigned short*)(ws + O_P3),
             1024, 128, nb >> 3, nb & 7,
             (float*)(ws + O_PEXP3) + (nb & 7) * 1024, (float*)(ws + O_DIAG3));
  }
}

// ================= dispatch C: final tree-reduce + combine (vectorized) =================
__global__ void __launch_bounds__(256) final_kernel(const char* __restrict__ ws,
                                                    float* __restrict__ out) {
  int tid = threadIdx.x;
  int wave = tid >> 6, lane = tid & 63;
  float v[7] = {0.f, 0.f, 0.f, 0.f, 0.f, 0.f, 0.f};
  {
    float4 a = ((const float4*)(ws + O_CECM))[tid];
    float4 bb = ((const float4*)(ws + O_CEM))[tid];
    float4 c = ((const float4*)(ws + O_CEC))[tid];
    v[0] = a.x + a.y + a.z + a.w;
    v[1] = bb.x + bb.y + bb.z + bb.w;
    v[2] = c.x + c.y + c.z + c.w;
  }
  for (int r = tid; r < 1024; r += 256) {          // 4096 word partials
    float4 wv = ((const float4*)(ws + O_WP2))[r];
    v[3] += wv.x + wv.y + wv.z + wv.w;
  }
  if (tid < 64) {                                   // 256 word-count partials
    float4 wc = ((const float4*)(ws + O_WC2))[tid];
    v[4] = wc.x + wc.y + wc.z + wc.w;
  }
  for (int r4 = tid; r4 < 1024; r4 += 256) {
    float4 S = {0.f, 0.f, 0.f, 0.f};
#pragma unroll
    for (int s = 0; s < 8; ++s) {
      float4 pv = ((const float4*)(ws + O_PEXP2))[s * 1024 + r4];
      S.x += pv.x; S.y += pv.y; S.z += pv.z; S.w += pv.w;
    }
    float4 dg = ((const float4*)(ws + O_DIAG2))[r4];
    v[5] += 4.0f * INV_T + __logf(S.x) + __logf(S.y) + __logf(S.z) + __logf(S.w)
            - LN2F * (dg.x + dg.y + dg.z + dg.w);
  }
  {
    int r4 = tid;
    float4 S = {0.f, 0.f, 0.f, 0.f};
#pragma unroll
    for (int s = 0; s < 8; ++s) {
      float4 pv = ((const float4*)(ws + O_PEXP3))[s * 256 + r4];
      S.x += pv.x; S.y += pv.y; S.z += pv.z; S.w += pv.w;
    }
    float4 dg = ((const float4*)(ws + O_DIAG3))[r4];
    v[6] = 4.0f * INV_T + __logf(S.x) + __logf(S.y) + __logf(S.z) + __logf(S.w)
           - LN2F * (dg.x + dg.y + dg.z + dg.w);
  }
#pragma unroll
  for (int j = 0; j < 7; ++j) {
    float x = v[j];
#pragma unroll
    for (int mm = 1; mm < 64; mm <<= 1) x += __shfl_xor(x, mm);
    v[j] = x;
  }
  __shared__ float fr[4][7];
  if (lane == 0)
#pragma unroll
    for (int j = 0; j < 7; ++j) fr[wave][j] = v[j];
  __syncthreads();
  if (tid == 0) {
    float s[7];
#pragma unroll
    for (int j = 0; j < 7; ++j) s[j] = fr[0][j] + fr[1][j] + fr[2][j] + fr[3][j];
    float n = s[1];
    float charL = (n > 0.f) ? (s[0] / fmaxf(n, 1.f)) : (s[2] / 32768.0f);
    float wordL = (s[4] > 0.f) ? (s[3] / fmaxf(s[4], 1.f)) : 0.f;
    out[0] = charL + 0.5f * wordL + 0.1f * (s[5] / 4096.0f) + 0.1f * (s[6] / 1024.0f);
  }
}

extern "C" void kernel_launch(void* const* d_in, const int* in_sizes, int n_in,
                              void* d_out, int out_size, void* d_ws, size_t ws_size,
                              hipStream_t stream) {
  (void)in_sizes; (void)n_in; (void)out_size; (void)ws_size;
  const float* logits        = (const float*)d_in[0];
  const float* word_preds    = (const float*)d_in[1];
  const float* char_features = (const float*)d_in[2];
  const float* c2            = (const float*)d_in[3];
  const float* c3            = (const float*)d_in[4];
  const int*   targets       = (const int*)d_in[5];
  const float* mask          = (const float*)d_in[6];
  float* out = (float*)d_out;
  char* ws = (char*)d_ws;

  fusedA_kernel<<<352, 256, SMEM_A, stream>>>(c2, c3, targets, ws);
  fusedB_kernel<<<7680, 256, SMEM_B, stream>>>(logits, word_preds, char_features,
                                               targets, mask, ws);
  final_kernel<<<1, 256, 0, stream>>>(ws, out);
}

// Round 6
// 173.693 us; speedup vs baseline: 1.0345x; 1.0345x over previous
//
#include <hip/hip_runtime.h>

#define SPACE_TOK 63
#define INV_T 14.285714285714286f          /* 1/0.07 */
#define SA_SCALE 20.609929155556595f       /* log2(e)/0.07 ; also the static max bound */
#define LN2F 0.6931471805599453f

typedef __attribute__((ext_vector_type(8))) short bf16x8;
typedef __attribute__((ext_vector_type(4))) float f32x4;

// ---- workspace byte offsets ----
#define O_CECM   0                         /* 1024 f */
#define O_CEM    4096                      /* 1024 f */
#define O_CEC    8192                      /* 1024 f */
#define O_WPART  12288                     /* 512 f */
#define O_WCNT   14336                     /* 32 f */
#define O_PEXP2  14464                     /* 8*4096 f -> ends 145536 */
#define O_DIAG2  145536                    /* 4096 f  -> 161920 */
#define O_PEXP3  161920                    /* 8*1024 f -> 194688 */
#define O_DIAG3  194688                    /* 1024 f  -> 198784 */
#define O_A2     198848                    /* swizzled bf16 */
#define SZ_A2    (4096*128*2)
#define O_P2     (O_A2 + SZ_A2)
#define O_A3     (O_P2 + SZ_A2)
#define SZ_A3    (1024*128*2)
#define O_P3     (O_A3 + SZ_A3)

#define SMEM_A   18048   /* max(norm 18048, word 5140, ce 48) */
#define NTILE    4
#define SMEM_NCE (4*64*17*4 + 4*64*4)   /* part 18496 + dpart 1024 = 19520 */

__device__ inline unsigned short f2bf(float x) {
  union { float f; unsigned int u; } c; c.f = x;
  unsigned int r = c.u + 0x7fffu + ((c.u >> 16) & 1u);
  return (unsigned short)(r >> 16);
}

// ================= norm: normalize+scale+bf16, fragment-swizzled =================
//   slot(row,c) = (row>>4)*2048 + (c>>5)*512 + (((c>>3)&3)*16 + (row&15))*8 + (c&7)
__device__ void norm_body(char* smem, const float* __restrict__ emb, int L,
                          unsigned short* __restrict__ Abf, unsigned short* __restrict__ Pbf,
                          int b, int l0) {
  float (*tile)[33] = (float(*)[33])smem;                 // 128*33*4 = 16896 B
  float (*np8)[32]  = (float(*)[32])(smem + 16896);       // 1024 B
  float* scl        = (float*)(smem + 16896 + 1024);      // 128 B
  int tid = threadIdx.x;
  int lx = tid & 31, cq = tid >> 5;
  const float* eb = emb + (size_t)b * 128 * L + l0;
  for (int c = cq; c < 128; c += 8) tile[c][lx] = eb[(size_t)c * L + lx];
  __syncthreads();
  {
    float s = 0.f;
    for (int c = cq; c < 128; c += 8) { float x = tile[c][lx]; s += x * x; }
    np8[cq][lx] = s;
  }
  __syncthreads();
  if (tid < 32) {
    float t = 0.f;
#pragma unroll
    for (int g = 0; g < 8; ++g) t += np8[g][tid];
    float nrm = fmaxf(sqrtf(t), 1e-12f);
    scl[tid] = ((tid & 1) ? 1.0f : SA_SCALE) / nrm;  // even l -> anchor (scaled)
  }
  __syncthreads();
  int c = tid & 127, lh = tid >> 7;
  int half = L >> 1;
  int k = c >> 5, quad = (c >> 3) & 3, j = c & 7;
  for (int lp = lh; lp < 32; lp += 2) {
    int l = l0 + lp;
    int row = b * half + (l >> 1);
    unsigned short v = f2bf(tile[c][lp] * scl[lp]);
    unsigned short* dst = (l & 1) ? Pbf : Abf;
    dst[(size_t)(row >> 4) * 2048 + k * 512 + ((quad << 4) + (row & 15)) * 8 + j] = v;
  }
}

// ================= word (R0 proven body: inline scan + segment loop) =================
__device__ void word_body(char* smem, const float* __restrict__ wp,
                          const float* __restrict__ cf,
                          const int* __restrict__ targets,
                          char* __restrict__ ws, int w) {
  int* sc      = (int*)smem;              // 1024 B
  int* splist  = (int*)(smem + 1024);     // 4096 B
  int* snext_sh = (int*)(smem + 5120);    // 4 B
  float* wacc  = (float*)(smem + 5124);   // 16 B
  int tid = threadIdx.x;
  int z = w & 15, tq = (w >> 4) & 3, b = w >> 6;
  const int* tb = targets + b * 4096;
  int tbase = tq * 1024;
  int4 tok = ((const int4*)(tb + tbase))[tid];
  int f0 = (tok.x == SPACE_TOK), f1 = (tok.y == SPACE_TOK),
      f2 = (tok.z == SPACE_TOK), f3 = (tok.w == SPACE_TOK);
  int cnt = f0 + f1 + f2 + f3;
  sc[tid] = cnt;
  __syncthreads();
  for (int off = 1; off < 256; off <<= 1) {
    int v = (tid >= off) ? sc[tid - off] : 0;
    __syncthreads();
    sc[tid] += v;
    __syncthreads();
  }
  int base = sc[tid] - cnt;
  int p = tbase + tid * 4;
  if (f0) splist[base++] = p;
  if (f1) splist[base++] = p + 1;
  if (f2) splist[base++] = p + 2;
  if (f3) splist[base++] = p + 3;
  int m = sc[255];
  if (tid == 0) *snext_sh = -1;
  __syncthreads();
  if (m > 0) {
    for (int wstart = tbase + 1024; wstart < 4096 && *snext_sh < 0; wstart += 1024) {
      int t = wstart + tid * 4;
      int4 tk = ((const int4*)tb)[t >> 2];
      int found = 0x7fffffff;
      if (tk.x == SPACE_TOK) found = t;
      else if (tk.y == SPACE_TOK) found = t + 1;
      else if (tk.z == SPACE_TOK) found = t + 2;
      else if (tk.w == SPACE_TOK) found = t + 3;
#pragma unroll
      for (int mm = 1; mm < 64; mm <<= 1) found = min(found, __shfl_xor(found, mm));
      if ((tid & 63) == 0) sc[tid >> 6] = found;
      __syncthreads();
      if (tid == 0) {
        int f = min(min(sc[0], sc[1]), min(sc[2], sc[3]));
        if (f != 0x7fffffff) *snext_sh = f;
      }
      __syncthreads();
    }
  }
  int snext = *snext_sh;
  int wave = tid >> 6, lane = tid & 63;
  int dbase = z * 32 + wave * 8;
  const float* r0 = cf + ((size_t)(b * 512 + dbase)) * 4096;
  float myacc = 0.f;
  float lcnt = 0.f;
  for (int i = 0; i < m; ++i) {
    int t0 = splist[i];
    int t1 = (i + 1 < m) ? splist[i + 1] : snext;
    if (t1 < 0) break;
    int seglen = t1 - t0 - 1;
    if (seglen <= 0) continue;
    lcnt += 1.0f;
    int wpos = t0 >> 1;
    float invc = 1.0f / (float)seglen;
    float pred = 0.f;
    if (lane < 8) pred = wp[((size_t)(b * 512 + dbase + lane)) * 2048 + wpos];
    int c0 = (t0 + 1) >> 2;
    int c1 = (t1 + 3) >> 2;
    float s0 = 0.f, s1 = 0.f, s2 = 0.f, s3 = 0.f, s4 = 0.f, s5 = 0.f, s6 = 0.f, s7 = 0.f;
    for (int c = c0 + lane; c < c1; c += 64) {
      int tbp = c << 2;
      float4 v0 = *(const float4*)(r0 + 0 * 4096 + tbp);
      float4 v1 = *(const float4*)(r0 + 1 * 4096 + tbp);
      float4 v2 = *(const float4*)(r0 + 2 * 4096 + tbp);
      float4 v3 = *(const float4*)(r0 + 3 * 4096 + tbp);
      float4 v4 = *(const float4*)(r0 + 4 * 4096 + tbp);
      float4 v5 = *(const float4*)(r0 + 5 * 4096 + tbp);
      float4 v6 = *(const float4*)(r0 + 6 * 4096 + tbp);
      float4 v7 = *(const float4*)(r0 + 7 * 4096 + tbp);
      float m0 = (tbp + 0 > t0 && tbp + 0 < t1) ? 1.f : 0.f;
      float m1 = (tbp + 1 > t0 && tbp + 1 < t1) ? 1.f : 0.f;
      float m2 = (tbp + 2 > t0 && tbp + 2 < t1) ? 1.f : 0.f;
      float m3 = (tbp + 3 > t0 && tbp + 3 < t1) ? 1.f : 0.f;
      s0 += v0.x * m0 + v0.y * m1 + v0.z * m2 + v0.w * m3;
      s1 += v1.x * m0 + v1.y * m1 + v1.z * m2 + v1.w * m3;
      s2 += v2.x * m0 + v2.y * m1 + v2.z * m2 + v2.w * m3;
      s3 += v3.x * m0 + v3.y * m1 + v3.z * m2 + v3.w * m3;
      s4 += v4.x * m0 + v4.y * m1 + v4.z * m2 + v4.w * m3;
      s5 += v5.x * m0 + v5.y * m1 + v5.z * m2 + v5.w * m3;
      s6 += v6.x * m0 + v6.y * m1 + v6.z * m2 + v6.w * m3;
      s7 += v7.x * m0 + v7.y * m1 + v7.z * m2 + v7.w * m3;
    }
#pragma unroll
    for (int mm = 1; mm < 64; mm <<= 1) {
      s0 += __shfl_xor(s0, mm); s1 += __shfl_xor(s1, mm);
      s2 += __shfl_xor(s2, mm); s3 += __shfl_xor(s3, mm);
      s4 += __shfl_xor(s4, mm); s5 += __shfl_xor(s5, mm);
      s6 += __shfl_xor(s6, mm); s7 += __shfl_xor(s7, mm);
    }
    if (lane < 8) {
      float sv = (lane == 0) ? s0 : (lane == 1) ? s1 : (lane == 2) ? s2 : (lane == 3) ? s3
               : (lane == 4) ? s4 : (lane == 5) ? s5 : (lane == 6) ? s6 : s7;
      float mean = sv * invc;
      float diff = pred - mean;
      myacc += diff * diff;
    }
  }
#pragma unroll
  for (int mm = 1; mm < 8; mm <<= 1) myacc += __shfl_xor(myacc, mm);
  if (lane == 0) wacc[wave] = myacc;
  __syncthreads();
  if (tid == 0) {
    ((float*)(ws + O_WPART))[w] = (wacc[0] + wacc[1] + wacc[2] + wacc[3]) * (1.0f / 512.0f);
    if (z == 0) ((float*)(ws + O_WCNT))[w >> 4] = lcnt;
  }
}

// ================= ce =================
__device__ void ce_body(char* smem, const float* __restrict__ logits,
                        const int* __restrict__ targets, const float* __restrict__ mask,
                        char* ws, int cb) {
  int tid = threadIdx.x;
  int wave = tid >> 6, lane = tid & 63;
  int rbase = cb * 32 + wave * 8;
  float4 v[8];
  float mk[8];
  int tg[8];
#pragma unroll
  for (int rr = 0; rr < 8; ++rr) v[rr] = ((const float4*)logits)[(size_t)(rbase + rr) * 64 + lane];
#pragma unroll
  for (int rr = 0; rr < 8; ++rr) { tg[rr] = targets[rbase + rr]; mk[rr] = mask[rbase + rr]; }
  float aCM = 0.f, aM = 0.f, aC = 0.f;
#pragma unroll
  for (int rr = 0; rr < 8; ++rr) {
    float e = __expf(v[rr].x) + __expf(v[rr].y) + __expf(v[rr].z) + __expf(v[rr].w);
#pragma unroll
    for (int m = 1; m < 64; m <<= 1) e += __shfl_xor(e, m);
    int t = tg[rr];
    int q = t & 3;
    float sel = (q == 0) ? v[rr].x : (q == 1) ? v[rr].y : (q == 2) ? v[rr].z : v[rr].w;
    float xt = __shfl(sel, t >> 2);
    float ce = __logf(e) - xt;
    aCM += ce * mk[rr]; aM += mk[rr]; aC += ce;
  }
  float (*red)[3] = (float(*)[3])smem;
  if (lane == 0) { red[wave][0] = aCM; red[wave][1] = aM; red[wave][2] = aC; }
  __syncthreads();
  if (tid == 0) {
    ((float*)(ws + O_CECM))[cb] = red[0][0] + red[1][0] + red[2][0] + red[3][0];
    ((float*)(ws + O_CEM ))[cb] = red[0][1] + red[1][1] + red[2][1] + red[3][1];
    ((float*)(ws + O_CEC ))[cb] = red[0][2] + red[1][2] + red[2][2] + red[3][2];
  }
}

// ====== dispatch A: word(512) | ce(1024) | norm2(256) | norm3(64) = 1856 blocks ======
// word/ce depend only on raw inputs; norm runs beside them. Only nce needs norm -> B.
__global__ void __launch_bounds__(256) fusedA_kernel(const float* __restrict__ logits,
                                                     const float* __restrict__ wp,
                                                     const float* __restrict__ cf,
                                                     const int* __restrict__ targets,
                                                     const float* __restrict__ mask,
                                                     const float* __restrict__ c2,
                                                     const float* __restrict__ c3,
                                                     char* __restrict__ ws) {
  extern __shared__ char smem[];
  int bid = blockIdx.x;
  if (bid < 512) {
    word_body(smem, wp, cf, targets, ws, bid);
  } else if (bid < 1536) {
    ce_body(smem, logits, targets, mask, ws, bid - 512);
  } else if (bid < 1792) {
    int nb = bid - 1536;
    norm_body(smem, c2, 1024, (unsigned short*)(ws + O_A2), (unsigned short*)(ws + O_P2),
              nb & 7, (nb >> 3) * 32);
  } else {
    int nb = bid - 1792;
    norm_body(smem, c3, 256, (unsigned short*)(ws + O_A3), (unsigned short*)(ws + O_P3),
              nb & 7, (nb >> 3) * 32);
  }
}

// ================= dispatch B: nce with 4 anchor-tiles per block ====================
// Each block: anchor group I0g = grp*64 (4 tiles of 16) x J-slice s. Every b-fragment
// load feeds 4 MFMAs -> P-operand L2/L3 traffic cut 4x (256 MB -> 64 MB for nce2).
__device__ void nce_body(char* smem, const unsigned short* __restrict__ A,
                         const unsigned short* __restrict__ P, int sliceJ,
                         int grp, int s, float* __restrict__ pexp,
                         float* __restrict__ diag) {
  int tid = threadIdx.x;
  int wave = tid >> 6, lane = tid & 63;
  int col = lane & 15, quad = lane >> 4;
  int I0g = grp * (16 * NTILE);
  const unsigned short* At = A + (size_t)(I0g >> 4) * 2048 + lane * 8;
  bf16x8 a[NTILE][4];
#pragma unroll
  for (int t = 0; t < NTILE; ++t)
#pragma unroll
    for (int k = 0; k < 4; ++k)
      a[t][k] = *(const bf16x8*)(At + t * 2048 + k * 512);
  float rl[NTILE][4];
#pragma unroll
  for (int t = 0; t < NTILE; ++t)
#pragma unroll
    for (int q = 0; q < 4; ++q) rl[t][q] = 0.f;
  float dcap[NTILE];
#pragma unroll
  for (int t = 0; t < NTILE; ++t) dcap[t] = 0.f;
  int perW = sliceJ >> 2;
  int J0w = s * sliceJ + wave * perW, Jend = J0w + perW;
  for (int J = J0w; J < Jend; J += 16) {
    const unsigned short* Pt = P + (size_t)(J >> 4) * 2048 + lane * 8;
    bf16x8 b0 = *(const bf16x8*)(Pt);
    bf16x8 b1 = *(const bf16x8*)(Pt + 512);
    bf16x8 b2 = *(const bf16x8*)(Pt + 1024);
    bf16x8 b3 = *(const bf16x8*)(Pt + 1536);
#pragma unroll
    for (int t = 0; t < NTILE; ++t) {
      f32x4 cfr = {0.f, 0.f, 0.f, 0.f};
      cfr = __builtin_amdgcn_mfma_f32_16x16x32_bf16(a[t][0], b0, cfr, 0, 0, 0);
      cfr = __builtin_amdgcn_mfma_f32_16x16x32_bf16(a[t][1], b1, cfr, 0, 0, 0);
      cfr = __builtin_amdgcn_mfma_f32_16x16x32_bf16(a[t][2], b2, cfr, 0, 0, 0);
      cfr = __builtin_amdgcn_mfma_f32_16x16x32_bf16(a[t][3], b3, cfr, 0, 0, 0);
      rl[t][0] += exp2f(cfr[0] - SA_SCALE);
      rl[t][1] += exp2f(cfr[1] - SA_SCALE);
      rl[t][2] += exp2f(cfr[2] - SA_SCALE);
      rl[t][3] += exp2f(cfr[3] - SA_SCALE);
      if (J == I0g + 16 * t) {
        int r = col - (quad << 2);
        if (r == 0) dcap[t] = cfr[0];
        else if (r == 1) dcap[t] = cfr[1];
        else if (r == 2) dcap[t] = cfr[2];
        else if (r == 3) dcap[t] = cfr[3];
      }
    }
  }
  float (*part)[64][17] = (float(*)[64][17])smem;            // 4*64*17*4 = 18496 B
  float (*dpart)[64]    = (float(*)[64])(smem + 18496);      // 1024 B
#pragma unroll
  for (int t = 0; t < NTILE; ++t) {
    part[wave][t * 16 + (quad << 2) + 0][col] = rl[t][0];
    part[wave][t * 16 + (quad << 2) + 1][col] = rl[t][1];
    part[wave][t * 16 + (quad << 2) + 2][col] = rl[t][2];
    part[wave][t * 16 + (quad << 2) + 3][col] = rl[t][3];
    if (quad == (col >> 2)) dpart[wave][t * 16 + col] = dcap[t];
  }
  __syncthreads();
  {
    int rrow = tid >> 4, cc = tid & 15;
#pragma unroll
    for (int t = 0; t < NTILE; ++t) {
      int row = t * 16 + rrow;
      float sv = 0.f, d = 0.f;
#pragma unroll
      for (int ww = 0; ww < 4; ++ww) { sv += part[ww][row][cc]; d += dpart[ww][row]; }
#pragma unroll
      for (int mm = 1; mm < 16; mm <<= 1) sv += __shfl_xor(sv, mm);
      if (cc == 0) {
        int gi = I0g + row;
        pexp[gi] = sv;
        if (gi >= s * sliceJ && gi < (s + 1) * sliceJ) diag[gi] = d;
      }
    }
  }
}

__global__ void __launch_bounds__(256) nce_kernel(char* __restrict__ ws) {
  extern __shared__ char smem[];
  int bid = blockIdx.x;
  if (bid < 512) {                       // nce2: 64 grps x 8 slices
    nce_body(smem, (const unsigned short*)(ws + O_A2), (const unsigned short*)(ws + O_P2),
             512, bid >> 3, bid & 7,
             (float*)(ws + O_PEXP2) + (bid & 7) * 4096, (float*)(ws + O_DIAG2));
  } else {                               // nce3: 16 grps x 8 slices
    int nb = bid - 512;
    nce_body(smem, (const unsigned short*)(ws + O_A3), (const unsigned short*)(ws + O_P3),
             128, nb >> 3, nb & 7,
             (float*)(ws + O_PEXP3) + (nb & 7) * 1024, (float*)(ws + O_DIAG3));
  }
}

// ================= dispatch C: final tree-reduce + combine (vectorized) =================
__global__ void __launch_bounds__(256) final_kernel(const char* __restrict__ ws,
                                                    float* __restrict__ out) {
  int tid = threadIdx.x;
  int wave = tid >> 6, lane = tid & 63;
  float v[7] = {0.f, 0.f, 0.f, 0.f, 0.f, 0.f, 0.f};
  {
    float4 a = ((const float4*)(ws + O_CECM))[tid];
    float4 bb = ((const float4*)(ws + O_CEM))[tid];
    float4 c = ((const float4*)(ws + O_CEC))[tid];
    v[0] = a.x + a.y + a.z + a.w;
    v[1] = bb.x + bb.y + bb.z + bb.w;
    v[2] = c.x + c.y + c.z + c.w;
  }
  if (tid < 128) {
    float4 wv = ((const float4*)(ws + O_WPART))[tid];
    v[3] = wv.x + wv.y + wv.z + wv.w;
  }
  if (tid < 32) v[4] = ((const float*)(ws + O_WCNT))[tid];
  for (int r4 = tid; r4 < 1024; r4 += 256) {
    float4 S = {0.f, 0.f, 0.f, 0.f};
#pragma unroll
    for (int s = 0; s < 8; ++s) {
      float4 pv = ((const float4*)(ws + O_PEXP2))[s * 1024 + r4];
      S.x += pv.x; S.y += pv.y; S.z += pv.z; S.w += pv.w;
    }
    float4 dg = ((const float4*)(ws + O_DIAG2))[r4];
    v[5] += 4.0f * INV_T + __logf(S.x) + __logf(S.y) + __logf(S.z) + __logf(S.w)
            - LN2F * (dg.x + dg.y + dg.z + dg.w);
  }
  {
    int r4 = tid;
    float4 S = {0.f, 0.f, 0.f, 0.f};
#pragma unroll
    for (int s = 0; s < 8; ++s) {
      float4 pv = ((const float4*)(ws + O_PEXP3))[s * 256 + r4];
      S.x += pv.x; S.y += pv.y; S.z += pv.z; S.w += pv.w;
    }
    float4 dg = ((const float4*)(ws + O_DIAG3))[r4];
    v[6] = 4.0f * INV_T + __logf(S.x) + __logf(S.y) + __logf(S.z) + __logf(S.w)
           - LN2F * (dg.x + dg.y + dg.z + dg.w);
  }
#pragma unroll
  for (int j = 0; j < 7; ++j) {
    float x = v[j];
#pragma unroll
    for (int mm = 1; mm < 64; mm <<= 1) x += __shfl_xor(x, mm);
    v[j] = x;
  }
  __shared__ float fr[4][7];
  if (lane == 0)
#pragma unroll
    for (int j = 0; j < 7; ++j) fr[wave][j] = v[j];
  __syncthreads();
  if (tid == 0) {
    float s[7];
#pragma unroll
    for (int j = 0; j < 7; ++j) s[j] = fr[0][j] + fr[1][j] + fr[2][j] + fr[3][j];
    float n = s[1];
    float charL = (n > 0.f) ? (s[0] / fmaxf(n, 1.f)) : (s[2] / 32768.0f);
    float wordL = (s[4] > 0.f) ? (s[3] / fmaxf(s[4], 1.f)) : 0.f;
    out[0] = charL + 0.5f * wordL + 0.1f * (s[5] / 4096.0f) + 0.1f * (s[6] / 1024.0f);
  }
}

extern "C" void kernel_launch(void* const* d_in, const int* in_sizes, int n_in,
                              void* d_out, int out_size, void* d_ws, size_t ws_size,
                              hipStream_t stream) {
  (void)in_sizes; (void)n_in; (void)out_size; (void)ws_size;
  const float* logits        = (const float*)d_in[0];
  const float* word_preds    = (const float*)d_in[1];
  const float* char_features = (const float*)d_in[2];
  const float* c2            = (const float*)d_in[3];
  const float* c3            = (const float*)d_in[4];
  const int*   targets       = (const int*)d_in[5];
  const float* mask          = (const float*)d_in[6];
  float* out = (float*)d_out;
  char* ws = (char*)d_ws;

  fusedA_kernel<<<1856, 256, SMEM_A, stream>>>(logits, word_preds, char_features,
                                               targets, mask, c2, c3, ws);
  nce_kernel<<<640, 256, SMEM_NCE, stream>>>(ws);
  final_kernel<<<1, 256, 0, stream>>>(ws, out);
}